// Round 12
// baseline (403.599 us; speedup 1.0000x reference)
//
#include <hip/hip_runtime.h>

#define Nn 50000
#define Ee 800000
#define Gg 1000
#define Hh 128
#define Cc 6
#define EPSf 1e-5f
#define SB 1024                       // elements per scan block
#define NSB ((Nn + SB - 1) / SB)      // 49
#define BINSH 12                      // fill bin = dst >> 12 (4096 nodes/bin)
#define NBIN 13                       // ceil(50000/4096)

typedef unsigned short u16;
typedef unsigned int u32;
typedef __attribute__((ext_vector_type(8))) short bf16x8;
typedef __attribute__((ext_vector_type(4))) float f32x4;

static __device__ inline u16 f2bf(float f) {
    u32 u = __float_as_uint(f);
    u32 r = (u + 0x7fffu + ((u >> 16) & 1u)) >> 16;   // RNE
    return (u16)r;
}
static __device__ inline float bf_lo(u32 v) { return __uint_as_float(v << 16); }
static __device__ inline float bf_hi(u32 v) { return __uint_as_float(v & 0xffff0000u); }
static __device__ inline u32 pack2(float a, float b) {
    return ((u32)f2bf(b) << 16) | (u32)f2bf(a);
}

// ---------------- prologue A: zero indeg+stats+binctr, W->bf16 W^T ----------------
__global__ __launch_bounds__(256) void k_pre(const float* __restrict__ W3,
                                             u16* __restrict__ WT3,
                                             int* __restrict__ indeg,
                                             float* __restrict__ stats3,
                                             int* __restrict__ binctr) {
    int t = blockIdx.x * blockDim.x + threadIdx.x;
    if (t < Nn) indeg[t] = 0;
    if (t < 3 * 2 * Hh) stats3[t] = 0.0f;
    if (t < NBIN) binctr[t] = 0;

    if (blockIdx.x < 3) {              // weight transpose for layer l = blockIdx.x
        __shared__ u16 tbuf[Hh * 136];
        int l = blockIdx.x;
        const float* W = W3 + l * Hh * Hh;
        u16* WT = WT3 + l * Hh * Hh;
        int tid = threadIdx.x;
#pragma unroll
        for (int i = 0; i < 16; i++) {
            int v = tid + 256 * i;     // float4 idx over 4096
            int r = v >> 5, c4 = v & 31;
            float4 d = ((const float4*)W)[v];
            u16* p = tbuf + r * 136 + c4 * 4;
            p[0] = f2bf(d.x); p[1] = f2bf(d.y); p[2] = f2bf(d.z); p[3] = f2bf(d.w);
        }
        __syncthreads();
#pragma unroll
        for (int i = 0; i < 64; i++) {
            int o = tid + 256 * i;     // u16 idx over 16384
            int n = o >> 7, k = o & 127;
            WT[o] = tbuf[k * 136 + n];
        }
    }
}

// ---------------- prologue B: in-degree histogram + x->bf16 cast (overlapped) ----------------
__global__ void k_deg(const int* __restrict__ ei, int* __restrict__ indeg,
                      const float* __restrict__ X, u16* __restrict__ Xh) {
    int t = blockIdx.x * blockDim.x + threadIdx.x;
    if (t < Nn * 32) {                 // cast x (float4 granular)
        float4 v = ((const float4*)X)[t];
        ushort4 o;
        o.x = f2bf(v.x); o.y = f2bf(v.y); o.z = f2bf(v.z); o.w = f2bf(v.w);
        ((ushort4*)Xh)[t] = o;
    }
    if (t < Ee) atomicAdd(&indeg[ei[Ee + t]], 1);
}

// ---------------- scan phase 1 + dis + gstart (fused) ----------------
__global__ __launch_bounds__(256) void k_scan1(const int* __restrict__ indeg,
                                               int* __restrict__ rs,
                                               int* __restrict__ bsum,
                                               float* __restrict__ dis,
                                               const int* __restrict__ batch,
                                               int* __restrict__ gstart) {
    __shared__ int ts[256];
    int b = blockIdx.x;
    int t = threadIdx.x;
    int base = b * SB + t * 4;
    int v[4] = {0, 0, 0, 0};
#pragma unroll
    for (int j = 0; j < 4; j++) {
        int i = base + j;
        if (i < Nn) { v[j] = indeg[i]; dis[i] = rsqrtf((float)v[j] + 1.0f); }
    }
    int g = b * 256 + t;
    if (g <= Gg) {
        int lo = 0, hi = Nn;
        while (lo < hi) {
            int mid = (lo + hi) >> 1;
            if (batch[mid] < g) lo = mid + 1; else hi = mid;
        }
        gstart[g] = lo;
    }
    int tsum = v[0] + v[1] + v[2] + v[3];
    ts[t] = tsum;
    __syncthreads();
    for (int off = 1; off < 256; off <<= 1) {
        int x = (t >= off) ? ts[t - off] : 0;
        __syncthreads();
        ts[t] += x;
        __syncthreads();
    }
    int run = (t == 0) ? 0 : ts[t - 1];
    if (t == 255) bsum[b] = ts[255];
#pragma unroll
    for (int j = 0; j < 4; j++) {
        int i = base + j;
        if (i < Nn) { rs[i] = run; run += v[j]; }
    }
}

// ---------------- scan phase 2: per-block redundant top-scan + add ----------------
__global__ __launch_bounds__(256) void k_scan2(int* __restrict__ rs,
                                               const int* __restrict__ bsum) {
    __shared__ int lboff[NSB];
    int t = threadIdx.x;
    if (t < 64) {
        int orig = (t < NSB) ? bsum[t] : 0;
        int v = orig;
#pragma unroll
        for (int off = 1; off < 64; off <<= 1) {
            int u = __shfl_up(v, off, 64);
            if (t >= off) v += u;
        }
        if (t < NSB) lboff[t] = v - orig;   // exclusive
    }
    __syncthreads();
    int i = blockIdx.x * blockDim.x + t;
    if (i < Nn) rs[i] += lboff[i >> 10];
}

// ---------------- fill pass B: bin edges by dst>>12 into staged records ----------------
// stage rec = {dstlocal:12 in hi16 | src:16 in lo16}; per-(block,bin) runs are
// contiguous -> near-1x store line fill. binctr = global per-bin cursors (zeroed).
__global__ __launch_bounds__(1024) void k_fillB(const int* __restrict__ ei,
                                                const int* __restrict__ rs,
                                                int* __restrict__ binctr,
                                                u32* __restrict__ stage,
                                                int* __restrict__ binoff_g) {
    __shared__ int cnt[NBIN], lofs[NBIN];
    int t = threadIdx.x;
    int e = blockIdx.x * 1024 + t;
    if (t < NBIN) cnt[t] = 0;
    __syncthreads();
    int s = 0, d = 0, bin = 0, lpos = 0;
    bool valid = e < Ee;
    if (valid) {
        s = ei[e];
        d = ei[Ee + e];
        bin = d >> BINSH;
        lpos = atomicAdd(&cnt[bin], 1);
    }
    __syncthreads();
    if (t < NBIN) {
        int start = rs[t << BINSH];               // bin start in edge space
        lofs[t] = start + atomicAdd(&binctr[t], cnt[t]);
    }
    if (blockIdx.x == 0 && t <= NBIN)
        binoff_g[t] = (t < NBIN) ? rs[t << BINSH] : Ee;   // immutable snapshot
    __syncthreads();
    if (valid)
        stage[lofs[bin] + lpos] = ((u32)(d & ((1 << BINSH) - 1)) << 16) | (u32)s;
}

// ---------------- fill pass C: bin-ordered scatter into final recs ----------------
// Staged records are bin-contiguous -> concurrent writes cluster into 13 hot
// 260KB regions (L2-resident) -> line-fill instead of 16x amplification.
__global__ __launch_bounds__(1024) void k_fillC(const u32* __restrict__ stage,
                                                const int* __restrict__ binoff_g,
                                                int* __restrict__ rs,
                                                const float* __restrict__ dis,
                                                u32* __restrict__ recs) {
    __shared__ int boff[NBIN + 1];
    int t = threadIdx.x;
    if (t <= NBIN) boff[t] = binoff_g[t];
    __syncthreads();
    int i = blockIdx.x * 1024 + t;
    if (i >= Ee) return;
    u32 rec = stage[i];
    int bin = 0;
#pragma unroll
    for (int b = 1; b < NBIN; b++) bin += (i >= boff[b]) ? 1 : 0;
    int s = rec & 0xffffu;
    int d = (bin << BINSH) + (int)(rec >> 16);
    int slot = atomicAdd(&rs[d], 1);
    float w = dis[s] * dis[d];
    recs[slot] = ((u32)f2bf(w) << 16) | (u32)s;
}

// ---------------- MFMA GEMM with optional fused BN-normalize on the A-path ----------------
__global__ __launch_bounds__(256) void k_gemm(const u16* __restrict__ Xin,
                                              const u16* __restrict__ WT,
                                              u16* __restrict__ Yh,
                                              const float* __restrict__ stats,
                                              const float* __restrict__ gam,
                                              const float* __restrict__ bet,
                                              int donorm) {
    __shared__ u16 wt[Hh * 136];
    __shared__ float s_scale[Hh], s_shift[Hh];
    int tid = threadIdx.x;
    if (donorm && tid < Hh) {
        float mu = stats[tid] * (1.0f / Nn);
        float var = stats[Hh + tid] * (1.0f / Nn) - mu * mu;
        float sc = rsqrtf(var + EPSf) * gam[tid];
        s_scale[tid] = sc;
        s_shift[tid] = bet[tid] - mu * sc;
    }
#pragma unroll
    for (int i = 0; i < 8; i++) {
        int v = tid + 256 * i;            // uint4 idx over 2048
        int n = v >> 4, k8 = v & 15;
        uint4 d = ((const uint4*)WT)[v];
        *((uint4*)(wt + n * 136 + k8 * 8)) = d;
    }
    __syncthreads();

    int wv = tid >> 6, lane = tid & 63;
    int m = lane & 15, q = lane >> 4;
    int row0 = blockIdx.x * 64 + wv * 16;
    int lrow = row0 + m;
    if (lrow >= Nn) lrow = Nn - 1;        // clamp load row; stores guarded
    const u16* xrow = Xin + lrow * Hh + q * 8;

    f32x4 acc[8] = {};
#pragma unroll
    for (int k0 = 0; k0 < Hh; k0 += 32) {
        bf16x8 a;
        if (donorm) {
            int cb = k0 + q * 8;
            uint4 p = *(const uint4*)(xrow + k0);
            float4 sc0 = *(const float4*)(s_scale + cb);
            float4 sc1 = *(const float4*)(s_scale + cb + 4);
            float4 sh0 = *(const float4*)(s_shift + cb);
            float4 sh1 = *(const float4*)(s_shift + cb + 4);
            float f0 = fmaxf(bf_lo(p.x) * sc0.x + sh0.x, 0.0f);
            float f1 = fmaxf(bf_hi(p.x) * sc0.y + sh0.y, 0.0f);
            float f2 = fmaxf(bf_lo(p.y) * sc0.z + sh0.z, 0.0f);
            float f3 = fmaxf(bf_hi(p.y) * sc0.w + sh0.w, 0.0f);
            float f4 = fmaxf(bf_lo(p.z) * sc1.x + sh1.x, 0.0f);
            float f5 = fmaxf(bf_hi(p.z) * sc1.y + sh1.y, 0.0f);
            float f6 = fmaxf(bf_lo(p.w) * sc1.z + sh1.z, 0.0f);
            float f7 = fmaxf(bf_hi(p.w) * sc1.w + sh1.w, 0.0f);
            union { bf16x8 v; u32 u[4]; } cv;
            cv.u[0] = pack2(f0, f1);
            cv.u[1] = pack2(f2, f3);
            cv.u[2] = pack2(f4, f5);
            cv.u[3] = pack2(f6, f7);
            a = cv.v;
        } else {
            a = *(const bf16x8*)(xrow + k0);
        }
#pragma unroll
        for (int t = 0; t < 8; t++) {
            bf16x8 b = *(const bf16x8*)(wt + (t * 16 + m) * 136 + k0 + q * 8);
            acc[t] = __builtin_amdgcn_mfma_f32_16x16x32_bf16(a, b, acc[t], 0, 0, 0);
        }
    }

    int orow0 = row0 + q * 4;
#pragma unroll
    for (int t = 0; t < 8; t++) {
#pragma unroll
        for (int r = 0; r < 4; r++) {
            int rr = orow0 + r;
            if (rr < Nn) Yh[rr * Hh + t * 16 + m] = f2bf(acc[t][r]);
        }
    }
}

// ---------------- CSR gather: one wave/node, shfl-broadcast recs, unroll 16 ----------------
__global__ __launch_bounds__(256) void k_gather(const u16* __restrict__ Yh,
                                                const float* __restrict__ dis,
                                                const float* __restrict__ bias,
                                                const int* __restrict__ rs,
                                                const u32* __restrict__ recs,
                                                u16* __restrict__ Ah) {
    int node = blockIdx.x * 4 + (threadIdx.x >> 6);
    if (node >= Nn) return;
    int lane = threadIdx.x & 63;

    const u32* rows = (const u32*)Yh;
    float dn = dis[node];
    u32 hv = rows[node * 64 + lane];
    float2 bv = ((const float2*)bias)[lane];
    float sn = dn * dn;
    float2 acc;
    acc.x = bf_lo(hv) * sn + bv.x;
    acc.y = bf_hi(hv) * sn + bv.y;

    int beg = (node == 0) ? 0 : rs[node - 1];
    int end = rs[node];

    for (int base = beg; base < end; base += 64) {
        int me = base + lane;
        u32 myrec = recs[me < end ? me : end - 1];   // one coalesced load / 64 edges
        int cnt = end - base;
        if (cnt > 64) cnt = 64;
        for (int i0 = 0; i0 < cnt; i0 += 16) {
            u32 rec[16]; float wgt[16]; u32 val[16];
#pragma unroll
            for (int i = 0; i < 16; i++) {
                int si = i0 + i;
                int sc = si < cnt ? si : cnt - 1;
                rec[i] = __shfl(myrec, sc, 64);
                wgt[i] = (si < cnt) ? __uint_as_float(rec[i] & 0xffff0000u) : 0.0f;
            }
#pragma unroll
            for (int i = 0; i < 16; i++) val[i] = rows[(rec[i] & 0xffffu) * 64 + lane];
#pragma unroll
            for (int i = 0; i < 16; i++) {
                acc.x += bf_lo(val[i]) * wgt[i];
                acc.y += bf_hi(val[i]) * wgt[i];
            }
        }
    }
    __builtin_nontemporal_store(pack2(acc.x, acc.y), (u32*)Ah + node * 64 + lane);
}

// ---------------- BN stats from row-major bf16: per-channel sum & sumsq, unroll 4 ----------------
__global__ __launch_bounds__(256) void k_stats(const u16* __restrict__ Ah,
                                               float* __restrict__ stats) {
    __shared__ float sh[4][256];
    int t = threadIdx.x;
    int jc = t & 63, ro = t >> 6;         // jc: u32-column (channels 2jc,2jc+1)
    const u32* col = (const u32*)Ah + jc;
    float sx = 0.f, sy = 0.f, qx = 0.f, qy = 0.f;
    for (int r = blockIdx.x * 16 + ro * 4; r < Nn; r += 4096) {
        u32 v[4];
#pragma unroll
        for (int k = 0; k < 4; k++) {
            int rr = r + k;
            v[k] = (rr < Nn) ? col[rr * 64] : 0u;
        }
#pragma unroll
        for (int k = 0; k < 4; k++) {
            float a = bf_lo(v[k]), b = bf_hi(v[k]);
            sx += a; sy += b; qx += a * a; qy += b * b;
        }
    }
    sh[0][t] = sx; sh[1][t] = sy; sh[2][t] = qx; sh[3][t] = qy;
    __syncthreads();
    if (t < 64) {
        sx = sh[0][t] + sh[0][t + 64] + sh[0][t + 128] + sh[0][t + 192];
        sy = sh[1][t] + sh[1][t + 64] + sh[1][t + 128] + sh[1][t + 192];
        qx = sh[2][t] + sh[2][t + 64] + sh[2][t + 128] + sh[2][t + 192];
        qy = sh[3][t] + sh[3][t + 64] + sh[3][t + 128] + sh[3][t + 192];
        atomicAdd(&stats[2 * t], sx);
        atomicAdd(&stats[2 * t + 1], sy);
        atomicAdd(&stats[Hh + 2 * t], qx);
        atomicAdd(&stats[Hh + 2 * t + 1], qy);
    }
}

// ---------------- fused BN-normalize + mean pool + MLP head: one block per graph ----------------
__global__ __launch_bounds__(128) void k_poolmlp(const u16* __restrict__ Ah,
                                                 const float* __restrict__ stats,
                                                 const float* __restrict__ gam,
                                                 const float* __restrict__ bet,
                                                 const int* __restrict__ gstart,
                                                 const float* __restrict__ W1,
                                                 const float* __restrict__ b1,
                                                 const float* __restrict__ W2,
                                                 const float* __restrict__ b2,
                                                 float* __restrict__ out) {
    int g = blockIdx.x;
    int c = threadIdx.x;
    __shared__ float p[Hh];
    __shared__ float hid[Hh];
    float mu = stats[c] * (1.0f / Nn);
    float var = stats[Hh + c] * (1.0f / Nn) - mu * mu;
    float sc = rsqrtf(var + EPSf) * gam[c];
    float sf = bet[c] - mu * sc;
    int s = gstart[g], e = gstart[g + 1];
    float sum = 0.0f;
    for (int r = s; r < e; r++) {
        float v = __uint_as_float((u32)Ah[r * Hh + c] << 16);
        sum += fmaxf(v * sc + sf, 0.0f);
    }
    int n = e - s;
    p[c] = sum / (float)(n > 1 ? n : 1);
    __syncthreads();
    float acc = b1[c];
    for (int k = 0; k < Hh; k++) acc += p[k] * W1[k * Hh + c];
    hid[c] = fmaxf(acc, 0.0f);
    __syncthreads();
    if (c < Cc) {
        float acc2 = b2[c];
        for (int k = 0; k < Hh; k++) acc2 += hid[k] * W2[k * Cc + c];
        out[g * Cc + c] = acc2;
    }
}

extern "C" void kernel_launch(void* const* d_in, const int* in_sizes, int n_in,
                              void* d_out, int out_size, void* d_ws, size_t ws_size,
                              hipStream_t stream) {
    const float* x      = (const float*)d_in[0];
    const int*   ei     = (const int*)d_in[1];
    const int*   batch  = (const int*)d_in[2];
    const float* conv_w = (const float*)d_in[3];
    const float* conv_b = (const float*)d_in[4];
    const float* bn_g   = (const float*)d_in[5];
    const float* bn_b   = (const float*)d_in[6];
    const float* w1     = (const float*)d_in[7];
    const float* b1     = (const float*)d_in[8];
    const float* w2     = (const float*)d_in[9];
    const float* b2     = (const float*)d_in[10];
    float* out = (float*)d_out;

    u16*   Xh      = (u16*)d_ws;                  // N*H bf16 (layer-0 gemm input)
    u16*   Yh      = Xh + Nn * Hh;                // N*H bf16 row-major (gemm out)
    u16*   Ah      = Yh + Nn * Hh;                // N*H bf16 row-major (gather out)
    u16*   WT      = Ah + Nn * Hh;                // 3*H*H bf16 (W^T)
    float* dis     = (float*)(WT + 3 * Hh * Hh);  // N
    float* stats3  = dis + Nn;                    // 3*2*H
    int*   indeg   = (int*)(stats3 + 3 * 2 * Hh); // N
    int*   rs      = indeg + Nn;                  // N
    int*   gstart  = rs + Nn;                     // G+1
    int*   bsum    = gstart + Gg + 1;             // NSB
    int*   binctr  = bsum + NSB;                  // NBIN
    int*   binoff  = binctr + NBIN;               // NBIN+1
    u32*   recs    = (u32*)(binoff + NBIN + 1);   // E packed 4B records
    u32*   stage   = recs + Ee;                   // E staged 4B records

    // ---- prologue + CSR build ----
    k_pre<<<(Nn + 255) / 256, 256, 0, stream>>>(conv_w, WT, indeg, stats3, binctr);
    k_deg<<<(Nn * 32 + 255) / 256, 256, 0, stream>>>(ei, indeg, x, Xh);
    k_scan1<<<NSB, 256, 0, stream>>>(indeg, rs, bsum, dis, batch, gstart);
    k_scan2<<<(Nn + 255) / 256, 256, 0, stream>>>(rs, bsum);
    k_fillB<<<(Ee + 1023) / 1024, 1024, 0, stream>>>(ei, rs, binctr, stage, binoff);
    k_fillC<<<(Ee + 1023) / 1024, 1024, 0, stream>>>(stage, binoff, rs, dis, recs);

    for (int l = 0; l < 3; l++) {
        float* stats = stats3 + l * 2 * Hh;
        const u16* gin = (l == 0) ? Xh : Ah;
        const float* pst = (l == 0) ? stats3 : stats3 + (l - 1) * 2 * Hh;
        const float* pg  = (l == 0) ? bn_g : bn_g + (l - 1) * Hh;
        const float* pb  = (l == 0) ? bn_b : bn_b + (l - 1) * Hh;
        k_gemm<<<(Nn + 63) / 64, 256, 0, stream>>>(gin, WT + l * Hh * Hh, Yh,
                                                   pst, pg, pb, (l == 0) ? 0 : 1);
        k_gather<<<(Nn + 3) / 4, 256, 0, stream>>>(Yh, dis, conv_b + l * Hh, rs,
                                                   recs, Ah);
        k_stats<<<256, 256, 0, stream>>>(Ah, stats);
    }

    k_poolmlp<<<Gg, 128, 0, stream>>>(Ah, stats3 + 2 * 2 * Hh, bn_g + 2 * Hh,
                                      bn_b + 2 * Hh, gstart, w1, b1, w2, b2, out);
}

// Round 13
// 389.160 us; speedup vs baseline: 1.0371x; 1.0371x over previous
//
#include <hip/hip_runtime.h>

#define Nn 50000
#define Ee 800000
#define Gg 1000
#define Hh 128
#define Cc 6
#define EPSf 1e-5f
#define SB 1024                       // elements per scan block
#define NSB ((Nn + SB - 1) / SB)      // 49

typedef unsigned short u16;
typedef unsigned int u32;
typedef __attribute__((ext_vector_type(8))) short bf16x8;
typedef __attribute__((ext_vector_type(4))) float f32x4;

static __device__ inline u16 f2bf(float f) {
    u32 u = __float_as_uint(f);
    u32 r = (u + 0x7fffu + ((u >> 16) & 1u)) >> 16;   // RNE
    return (u16)r;
}
static __device__ inline float bf_lo(u32 v) { return __uint_as_float(v << 16); }
static __device__ inline float bf_hi(u32 v) { return __uint_as_float(v & 0xffff0000u); }
static __device__ inline u32 pack2(float a, float b) {
    return ((u32)f2bf(b) << 16) | (u32)f2bf(a);
}

// ---------------- prologue A: zero indeg+stats, W->bf16 W^T ----------------
__global__ __launch_bounds__(256) void k_pre(const float* __restrict__ W3,
                                             u16* __restrict__ WT3,
                                             int* __restrict__ indeg,
                                             float* __restrict__ stats3) {
    int t = blockIdx.x * blockDim.x + threadIdx.x;
    if (t < Nn) indeg[t] = 0;
    if (t < 3 * 2 * Hh) stats3[t] = 0.0f;

    if (blockIdx.x < 3) {              // weight transpose for layer l = blockIdx.x
        __shared__ u16 tbuf[Hh * 136];
        int l = blockIdx.x;
        const float* W = W3 + l * Hh * Hh;
        u16* WT = WT3 + l * Hh * Hh;
        int tid = threadIdx.x;
#pragma unroll
        for (int i = 0; i < 16; i++) {
            int v = tid + 256 * i;     // float4 idx over 4096
            int r = v >> 5, c4 = v & 31;
            float4 d = ((const float4*)W)[v];
            u16* p = tbuf + r * 136 + c4 * 4;
            p[0] = f2bf(d.x); p[1] = f2bf(d.y); p[2] = f2bf(d.z); p[3] = f2bf(d.w);
        }
        __syncthreads();
#pragma unroll
        for (int i = 0; i < 64; i++) {
            int o = tid + 256 * i;     // u16 idx over 16384
            int n = o >> 7, k = o & 127;
            WT[o] = tbuf[k * 136 + n];
        }
    }
}

// ---------------- prologue B: in-degree histogram + x->bf16 cast (overlapped) ----------------
__global__ void k_deg(const int* __restrict__ ei, int* __restrict__ indeg,
                      const float* __restrict__ X, u16* __restrict__ Xh) {
    int t = blockIdx.x * blockDim.x + threadIdx.x;
    if (t < Nn * 32) {                 // cast x (float4 granular)
        float4 v = ((const float4*)X)[t];
        ushort4 o;
        o.x = f2bf(v.x); o.y = f2bf(v.y); o.z = f2bf(v.z); o.w = f2bf(v.w);
        ((ushort4*)Xh)[t] = o;
    }
    if (t < Ee) atomicAdd(&indeg[ei[Ee + t]], 1);
}

// ---------------- scan phase 1 + dis + gstart (fused) ----------------
__global__ __launch_bounds__(256) void k_scan1(const int* __restrict__ indeg,
                                               int* __restrict__ rs,
                                               int* __restrict__ bsum,
                                               float* __restrict__ dis,
                                               const int* __restrict__ batch,
                                               int* __restrict__ gstart) {
    __shared__ int ts[256];
    int b = blockIdx.x;
    int t = threadIdx.x;
    int base = b * SB + t * 4;
    int v[4] = {0, 0, 0, 0};
#pragma unroll
    for (int j = 0; j < 4; j++) {
        int i = base + j;
        if (i < Nn) { v[j] = indeg[i]; dis[i] = rsqrtf((float)v[j] + 1.0f); }
    }
    int g = b * 256 + t;
    if (g <= Gg) {
        int lo = 0, hi = Nn;
        while (lo < hi) {
            int mid = (lo + hi) >> 1;
            if (batch[mid] < g) lo = mid + 1; else hi = mid;
        }
        gstart[g] = lo;
    }
    int tsum = v[0] + v[1] + v[2] + v[3];
    ts[t] = tsum;
    __syncthreads();
    for (int off = 1; off < 256; off <<= 1) {
        int x = (t >= off) ? ts[t - off] : 0;
        __syncthreads();
        ts[t] += x;
        __syncthreads();
    }
    int run = (t == 0) ? 0 : ts[t - 1];
    if (t == 255) bsum[b] = ts[255];
#pragma unroll
    for (int j = 0; j < 4; j++) {
        int i = base + j;
        if (i < Nn) { rs[i] = run; run += v[j]; }
    }
}

// ---------------- scan phase 2: per-block redundant top-scan + add ----------------
__global__ __launch_bounds__(256) void k_scan2(int* __restrict__ rs,
                                               const int* __restrict__ bsum) {
    __shared__ int lboff[NSB];
    int t = threadIdx.x;
    if (t < 64) {
        int orig = (t < NSB) ? bsum[t] : 0;
        int v = orig;
#pragma unroll
        for (int off = 1; off < 64; off <<= 1) {
            int u = __shfl_up(v, off, 64);
            if (t >= off) v += u;
        }
        if (t < NSB) lboff[t] = v - orig;   // exclusive
    }
    __syncthreads();
    int i = blockIdx.x * blockDim.x + t;
    if (i < Nn) rs[i] += lboff[i >> 10];
}

// ---------------- counting-sort fill: 4B packed {w:bf16 | src:u16} ----------------
// After this kernel rs[d] == end of segment d.  (Single-pass: binned two-pass
// and NT-store variants both measured worse — cross-XCD write amplification
// on a 4B scatter is structural; see rounds 7 and 12.)
__global__ void k_fill(const int* __restrict__ ei, int* __restrict__ rs,
                       const float* __restrict__ dis, u32* __restrict__ recs) {
    int e = blockIdx.x * blockDim.x + threadIdx.x;
    if (e >= Ee) return;
    int s = ei[e];
    int d = ei[Ee + e];
    int slot = atomicAdd(&rs[d], 1);
    float w = dis[s] * dis[d];
    recs[slot] = ((u32)f2bf(w) << 16) | (u32)s;   // s < 50000 < 65536
}

// ---------------- MFMA GEMM with optional fused BN-normalize on the A-path ----------------
__global__ __launch_bounds__(256) void k_gemm(const u16* __restrict__ Xin,
                                              const u16* __restrict__ WT,
                                              u16* __restrict__ Yh,
                                              const float* __restrict__ stats,
                                              const float* __restrict__ gam,
                                              const float* __restrict__ bet,
                                              int donorm) {
    __shared__ u16 wt[Hh * 136];
    __shared__ float s_scale[Hh], s_shift[Hh];
    int tid = threadIdx.x;
    if (donorm && tid < Hh) {
        float mu = stats[tid] * (1.0f / Nn);
        float var = stats[Hh + tid] * (1.0f / Nn) - mu * mu;
        float sc = rsqrtf(var + EPSf) * gam[tid];
        s_scale[tid] = sc;
        s_shift[tid] = bet[tid] - mu * sc;
    }
#pragma unroll
    for (int i = 0; i < 8; i++) {
        int v = tid + 256 * i;            // uint4 idx over 2048
        int n = v >> 4, k8 = v & 15;
        uint4 d = ((const uint4*)WT)[v];
        *((uint4*)(wt + n * 136 + k8 * 8)) = d;
    }
    __syncthreads();

    int wv = tid >> 6, lane = tid & 63;
    int m = lane & 15, q = lane >> 4;
    int row0 = blockIdx.x * 64 + wv * 16;
    int lrow = row0 + m;
    if (lrow >= Nn) lrow = Nn - 1;        // clamp load row; stores guarded
    const u16* xrow = Xin + lrow * Hh + q * 8;

    f32x4 acc[8] = {};
#pragma unroll
    for (int k0 = 0; k0 < Hh; k0 += 32) {
        bf16x8 a;
        if (donorm) {
            int cb = k0 + q * 8;
            uint4 p = *(const uint4*)(xrow + k0);
            float4 sc0 = *(const float4*)(s_scale + cb);
            float4 sc1 = *(const float4*)(s_scale + cb + 4);
            float4 sh0 = *(const float4*)(s_shift + cb);
            float4 sh1 = *(const float4*)(s_shift + cb + 4);
            float f0 = fmaxf(bf_lo(p.x) * sc0.x + sh0.x, 0.0f);
            float f1 = fmaxf(bf_hi(p.x) * sc0.y + sh0.y, 0.0f);
            float f2 = fmaxf(bf_lo(p.y) * sc0.z + sh0.z, 0.0f);
            float f3 = fmaxf(bf_hi(p.y) * sc0.w + sh0.w, 0.0f);
            float f4 = fmaxf(bf_lo(p.z) * sc1.x + sh1.x, 0.0f);
            float f5 = fmaxf(bf_hi(p.z) * sc1.y + sh1.y, 0.0f);
            float f6 = fmaxf(bf_lo(p.w) * sc1.z + sh1.z, 0.0f);
            float f7 = fmaxf(bf_hi(p.w) * sc1.w + sh1.w, 0.0f);
            union { bf16x8 v; u32 u[4]; } cv;
            cv.u[0] = pack2(f0, f1);
            cv.u[1] = pack2(f2, f3);
            cv.u[2] = pack2(f4, f5);
            cv.u[3] = pack2(f6, f7);
            a = cv.v;
        } else {
            a = *(const bf16x8*)(xrow + k0);
        }
#pragma unroll
        for (int t = 0; t < 8; t++) {
            bf16x8 b = *(const bf16x8*)(wt + (t * 16 + m) * 136 + k0 + q * 8);
            acc[t] = __builtin_amdgcn_mfma_f32_16x16x32_bf16(a, b, acc[t], 0, 0, 0);
        }
    }

    int orow0 = row0 + q * 4;
#pragma unroll
    for (int t = 0; t < 8; t++) {
#pragma unroll
        for (int r = 0; r < 4; r++) {
            int rr = orow0 + r;
            if (rr < Nn) Yh[rr * Hh + t * 16 + m] = f2bf(acc[t][r]);
        }
    }
}

// ---------------- CSR gather: one wave/node, shfl-broadcast recs, unroll 16 ----------------
__global__ __launch_bounds__(256) void k_gather(const u16* __restrict__ Yh,
                                                const float* __restrict__ dis,
                                                const float* __restrict__ bias,
                                                const int* __restrict__ rs,
                                                const u32* __restrict__ recs,
                                                u16* __restrict__ Ah) {
    int node = blockIdx.x * 4 + (threadIdx.x >> 6);
    if (node >= Nn) return;
    int lane = threadIdx.x & 63;

    const u32* rows = (const u32*)Yh;
    float dn = dis[node];
    u32 hv = rows[node * 64 + lane];
    float2 bv = ((const float2*)bias)[lane];
    float sn = dn * dn;
    float2 acc;
    acc.x = bf_lo(hv) * sn + bv.x;
    acc.y = bf_hi(hv) * sn + bv.y;

    int beg = (node == 0) ? 0 : rs[node - 1];
    int end = rs[node];

    for (int base = beg; base < end; base += 64) {
        int me = base + lane;
        u32 myrec = recs[me < end ? me : end - 1];   // one coalesced load / 64 edges
        int cnt = end - base;
        if (cnt > 64) cnt = 64;
        for (int i0 = 0; i0 < cnt; i0 += 16) {
            u32 rec[16]; float wgt[16]; u32 val[16];
#pragma unroll
            for (int i = 0; i < 16; i++) {
                int si = i0 + i;
                int sc = si < cnt ? si : cnt - 1;
                rec[i] = __shfl(myrec, sc, 64);
                wgt[i] = (si < cnt) ? __uint_as_float(rec[i] & 0xffff0000u) : 0.0f;
            }
#pragma unroll
            for (int i = 0; i < 16; i++) val[i] = rows[(rec[i] & 0xffffu) * 64 + lane];
#pragma unroll
            for (int i = 0; i < 16; i++) {
                acc.x += bf_lo(val[i]) * wgt[i];
                acc.y += bf_hi(val[i]) * wgt[i];
            }
        }
    }
    __builtin_nontemporal_store(pack2(acc.x, acc.y), (u32*)Ah + node * 64 + lane);
}

// ---------------- BN stats from row-major bf16: per-channel sum & sumsq, unroll 4 ----------------
__global__ __launch_bounds__(256) void k_stats(const u16* __restrict__ Ah,
                                               float* __restrict__ stats) {
    __shared__ float sh[4][256];
    int t = threadIdx.x;
    int jc = t & 63, ro = t >> 6;         // jc: u32-column (channels 2jc,2jc+1)
    const u32* col = (const u32*)Ah + jc;
    float sx = 0.f, sy = 0.f, qx = 0.f, qy = 0.f;
    for (int r = blockIdx.x * 16 + ro * 4; r < Nn; r += 4096) {
        u32 v[4];
#pragma unroll
        for (int k = 0; k < 4; k++) {
            int rr = r + k;
            v[k] = (rr < Nn) ? col[rr * 64] : 0u;
        }
#pragma unroll
        for (int k = 0; k < 4; k++) {
            float a = bf_lo(v[k]), b = bf_hi(v[k]);
            sx += a; sy += b; qx += a * a; qy += b * b;
        }
    }
    sh[0][t] = sx; sh[1][t] = sy; sh[2][t] = qx; sh[3][t] = qy;
    __syncthreads();
    if (t < 64) {
        sx = sh[0][t] + sh[0][t + 64] + sh[0][t + 128] + sh[0][t + 192];
        sy = sh[1][t] + sh[1][t + 64] + sh[1][t + 128] + sh[1][t + 192];
        qx = sh[2][t] + sh[2][t + 64] + sh[2][t + 128] + sh[2][t + 192];
        qy = sh[3][t] + sh[3][t + 64] + sh[3][t + 128] + sh[3][t + 192];
        atomicAdd(&stats[2 * t], sx);
        atomicAdd(&stats[2 * t + 1], sy);
        atomicAdd(&stats[Hh + 2 * t], qx);
        atomicAdd(&stats[Hh + 2 * t + 1], qy);
    }
}

// ---------------- fused BN-normalize + mean pool + MLP head: one block per graph ----------------
__global__ __launch_bounds__(128) void k_poolmlp(const u16* __restrict__ Ah,
                                                 const float* __restrict__ stats,
                                                 const float* __restrict__ gam,
                                                 const float* __restrict__ bet,
                                                 const int* __restrict__ gstart,
                                                 const float* __restrict__ W1,
                                                 const float* __restrict__ b1,
                                                 const float* __restrict__ W2,
                                                 const float* __restrict__ b2,
                                                 float* __restrict__ out) {
    int g = blockIdx.x;
    int c = threadIdx.x;
    __shared__ float p[Hh];
    __shared__ float hid[Hh];
    float mu = stats[c] * (1.0f / Nn);
    float var = stats[Hh + c] * (1.0f / Nn) - mu * mu;
    float sc = rsqrtf(var + EPSf) * gam[c];
    float sf = bet[c] - mu * sc;
    int s = gstart[g], e = gstart[g + 1];
    float sum = 0.0f;
    for (int r = s; r < e; r++) {
        float v = __uint_as_float((u32)Ah[r * Hh + c] << 16);
        sum += fmaxf(v * sc + sf, 0.0f);
    }
    int n = e - s;
    p[c] = sum / (float)(n > 1 ? n : 1);
    __syncthreads();
    float acc = b1[c];
    for (int k = 0; k < Hh; k++) acc += p[k] * W1[k * Hh + c];
    hid[c] = fmaxf(acc, 0.0f);
    __syncthreads();
    if (c < Cc) {
        float acc2 = b2[c];
        for (int k = 0; k < Hh; k++) acc2 += hid[k] * W2[k * Cc + c];
        out[g * Cc + c] = acc2;
    }
}

extern "C" void kernel_launch(void* const* d_in, const int* in_sizes, int n_in,
                              void* d_out, int out_size, void* d_ws, size_t ws_size,
                              hipStream_t stream) {
    const float* x      = (const float*)d_in[0];
    const int*   ei     = (const int*)d_in[1];
    const int*   batch  = (const int*)d_in[2];
    const float* conv_w = (const float*)d_in[3];
    const float* conv_b = (const float*)d_in[4];
    const float* bn_g   = (const float*)d_in[5];
    const float* bn_b   = (const float*)d_in[6];
    const float* w1     = (const float*)d_in[7];
    const float* b1     = (const float*)d_in[8];
    const float* w2     = (const float*)d_in[9];
    const float* b2     = (const float*)d_in[10];
    float* out = (float*)d_out;

    u16*   Xh      = (u16*)d_ws;                  // N*H bf16 (layer-0 gemm input)
    u16*   Yh      = Xh + Nn * Hh;                // N*H bf16 row-major (gemm out)
    u16*   Ah      = Yh + Nn * Hh;                // N*H bf16 row-major (gather out)
    u16*   WT      = Ah + Nn * Hh;                // 3*H*H bf16 (W^T)
    float* dis     = (float*)(WT + 3 * Hh * Hh);  // N
    float* stats3  = dis + Nn;                    // 3*2*H
    int*   indeg   = (int*)(stats3 + 3 * 2 * Hh); // N
    int*   rs      = indeg + Nn;                  // N
    int*   gstart  = rs + Nn;                     // G+1
    int*   bsum    = gstart + Gg + 1;             // NSB
    u32*   recs    = (u32*)(bsum + NSB);          // E packed 4B records

    // ---- prologue + CSR build ----
    k_pre<<<(Nn + 255) / 256, 256, 0, stream>>>(conv_w, WT, indeg, stats3);
    k_deg<<<(Nn * 32 + 255) / 256, 256, 0, stream>>>(ei, indeg, x, Xh);
    k_scan1<<<NSB, 256, 0, stream>>>(indeg, rs, bsum, dis, batch, gstart);
    k_scan2<<<(Nn + 255) / 256, 256, 0, stream>>>(rs, bsum);
    k_fill<<<(Ee + 255) / 256, 256, 0, stream>>>(ei, rs, dis, recs);

    for (int l = 0; l < 3; l++) {
        float* stats = stats3 + l * 2 * Hh;
        const u16* gin = (l == 0) ? Xh : Ah;
        const float* pst = (l == 0) ? stats3 : stats3 + (l - 1) * 2 * Hh;
        const float* pg  = (l == 0) ? bn_g : bn_g + (l - 1) * Hh;
        const float* pb  = (l == 0) ? bn_b : bn_b + (l - 1) * Hh;
        k_gemm<<<(Nn + 63) / 64, 256, 0, stream>>>(gin, WT + l * Hh * Hh, Yh,
                                                   pst, pg, pb, (l == 0) ? 0 : 1);
        k_gather<<<(Nn + 3) / 4, 256, 0, stream>>>(Yh, dis, conv_b + l * Hh, rs,
                                                   recs, Ah);
        k_stats<<<256, 256, 0, stream>>>(Ah, stats);
    }

    k_poolmlp<<<Gg, 128, 0, stream>>>(Ah, stats3 + 2 * 2 * Hh, bn_g + 2 * Hh,
                                      bn_b + 2 * Hh, gstart, w1, b1, w2, b2, out);
}